// Round 1
// baseline (427.411 us; speedup 1.0000x reference)
//
#include <hip/hip_runtime.h>
#include <math.h>

#define NSAMP 8
#define CH 64
#define HH 64
#define WW 64
#define SPATIAL 4096        // HH*WW
#define PER_SAMPLE 262144   // CH*SPATIAL
#define NTOK 32768          // NSAMP*SPATIAL
#define NHEADS 4
#define HD 16
#define KS 7
#define EPS 1e-5f
#define QSCALE 0.25f        // HD^-0.5

// ---------------- K1: per-sample sum / sumsq ----------------
__global__ __launch_bounds__(256) void k_stats(const float* __restrict__ x,
                                               float* __restrict__ stats) {
    int blk = blockIdx.x;           // 256 blocks: 8 samples x 32 chunks
    int n = blk >> 5, chunk = blk & 31;
    const float4* p4 = (const float4*)(x + n * PER_SAMPLE + chunk * 8192);
    int t = threadIdx.x;
    float s1 = 0.f, s2 = 0.f;
#pragma unroll
    for (int i = 0; i < 8; i++) {
        float4 v = p4[t + i * 256];
        s1 += v.x + v.y + v.z + v.w;
        s2 += v.x * v.x + v.y * v.y + v.z * v.z + v.w * v.w;
    }
#pragma unroll
    for (int off = 1; off < 64; off <<= 1) {
        s1 += __shfl_xor(s1, off);
        s2 += __shfl_xor(s2, off);
    }
    __shared__ float r1[4], r2[4];
    int lane = t & 63, wv = t >> 6;
    if (lane == 0) { r1[wv] = s1; r2[wv] = s2; }
    __syncthreads();
    if (t == 0) {
        atomicAdd(&stats[n * 2 + 0], r1[0] + r1[1] + r1[2] + r1[3]);
        atomicAdd(&stats[n * 2 + 1], r2[0] + r2[1] + r2[2] + r2[3]);
    }
}

// ---------------- K2: norm + QKV GEMM ----------------
// block = 64 consecutive tokens of one sample; thread: token = t&63, jg = t>>6
__global__ __launch_bounds__(256) void k_qkv(const float* __restrict__ x,
                                             const float* __restrict__ stats,
                                             const float* __restrict__ gn_w,
                                             const float* __restrict__ gn_b,
                                             const float* __restrict__ qkv_w,
                                             const float* __restrict__ qkv_b,
                                             float* __restrict__ qkv) {
    int s0 = blockIdx.x * 64;
    int n = s0 >> 12, sp = s0 & 4095;
    int t = threadIdx.x, tok = t & 63, jg = t >> 6;
    float mu = stats[2 * n] * (1.f / (float)PER_SAMPLE);
    float var = stats[2 * n + 1] * (1.f / (float)PER_SAMPLE) - mu * mu;
    float rstd = rsqrtf(var + EPS);

    const float* xp = x + n * PER_SAMPLE + sp + tok;
    float xv[64];
#pragma unroll
    for (int c = 0; c < 64; c++)
        xv[c] = (xp[c * SPATIAL] - mu) * rstd * gn_w[c] + gn_b[c];

    int j0 = jg * 48;
    float* op = qkv + (size_t)(s0 + tok) * 192 + j0;
    for (int k = 0; k < 48; k++) {
        int j = j0 + k;
        const float* wr = qkv_w + j * 64;
        float s = qkv_b[j];
#pragma unroll
        for (int c = 0; c < 64; c++) s += xv[c] * wr[c];
        if (j < 64) s *= QSCALE;   // scale q
        op[k] = s;
    }
}

// ---------------- K3: neighborhood attention ----------------
// block = one (sample,row): 4 waves = 4 heads, lane = column
__global__ __launch_bounds__(256) void k_attn(const float* __restrict__ qkv,
                                              const float* __restrict__ rpb,
                                              float* __restrict__ attnout) {
    int b = blockIdx.x;             // 512 = 8 samples * 64 rows
    int n = b >> 6, h = b & 63;
    int t = threadIdx.x, head = t >> 6, w = t & 63;
    int tok = (n * 64 + h) * 64 + w;

    const float4* qp = (const float4*)(qkv + (size_t)tok * 192 + head * 16);
    float q[16];
#pragma unroll
    for (int i = 0; i < 4; i++) {
        float4 v = qp[i];
        q[4 * i] = v.x; q[4 * i + 1] = v.y; q[4 * i + 2] = v.z; q[4 * i + 3] = v.w;
    }
    int sh = min(max(h - 3, 0), HH - KS);
    int sw = min(max(w - 3, 0), WW - KS);

    float lg[49];
    float mx = -1e30f;
#pragma unroll
    for (int a = 0; a < 7; a++) {
        int row = sh + a;
        int rh = h - sh + 6 - a;
        const float* rp = rpb + (head * 13 + rh) * 13;
#pragma unroll
        for (int bb = 0; bb < 7; bb++) {
            int col = sw + bb;
            const float4* kp = (const float4*)(qkv + (size_t)((n * 64 + row) * 64 + col) * 192 + 64 + head * 16);
            float4 k0 = kp[0], k1 = kp[1], k2 = kp[2], k3 = kp[3];
            float d = q[0] * k0.x + q[1] * k0.y + q[2] * k0.z + q[3] * k0.w
                    + q[4] * k1.x + q[5] * k1.y + q[6] * k1.z + q[7] * k1.w
                    + q[8] * k2.x + q[9] * k2.y + q[10] * k2.z + q[11] * k2.w
                    + q[12] * k3.x + q[13] * k3.y + q[14] * k3.z + q[15] * k3.w;
            int rw = w - sw + 6 - bb;
            d += rp[rw];
            lg[a * 7 + bb] = d;
            mx = fmaxf(mx, d);
        }
    }
    float sum = 0.f;
#pragma unroll
    for (int i = 0; i < 49; i++) {
        float e = __expf(lg[i] - mx);
        lg[i] = e;
        sum += e;
    }
    float rs = 1.f / sum;

    float acc[16];
#pragma unroll
    for (int i = 0; i < 16; i++) acc[i] = 0.f;
#pragma unroll
    for (int a = 0; a < 7; a++) {
        int row = sh + a;
#pragma unroll
        for (int bb = 0; bb < 7; bb++) {
            int col = sw + bb;
            const float4* vp = (const float4*)(qkv + (size_t)((n * 64 + row) * 64 + col) * 192 + 128 + head * 16);
            float p = lg[a * 7 + bb];
            float4 v0 = vp[0], v1 = vp[1], v2 = vp[2], v3 = vp[3];
            acc[0] += p * v0.x; acc[1] += p * v0.y; acc[2] += p * v0.z; acc[3] += p * v0.w;
            acc[4] += p * v1.x; acc[5] += p * v1.y; acc[6] += p * v1.z; acc[7] += p * v1.w;
            acc[8] += p * v2.x; acc[9] += p * v2.y; acc[10] += p * v2.z; acc[11] += p * v2.w;
            acc[12] += p * v3.x; acc[13] += p * v3.y; acc[14] += p * v3.z; acc[15] += p * v3.w;
        }
    }
    float4* outp = (float4*)(attnout + (size_t)tok * 64 + head * 16);
#pragma unroll
    for (int i = 0; i < 4; i++) {
        float4 v;
        v.x = acc[4 * i] * rs; v.y = acc[4 * i + 1] * rs;
        v.z = acc[4 * i + 2] * rs; v.w = acc[4 * i + 3] * rs;
        outp[i] = v;
    }
}

// ---------------- K4: proj GEMM + residual (x transposed read) ----------------
__global__ __launch_bounds__(256) void k_proj(const float* __restrict__ attnout,
                                              const float* __restrict__ proj_w,
                                              const float* __restrict__ proj_b,
                                              const float* __restrict__ x,
                                              float* __restrict__ y) {
    int s0 = blockIdx.x * 64;
    int n = s0 >> 12, sp = s0 & 4095;
    int t = threadIdx.x, tok = t & 63, cg = t >> 6;

    float av[64];
    const float4* ap = (const float4*)(attnout + (size_t)(s0 + tok) * 64);
#pragma unroll
    for (int i = 0; i < 16; i++) {
        float4 v = ap[i];
        av[4 * i] = v.x; av[4 * i + 1] = v.y; av[4 * i + 2] = v.z; av[4 * i + 3] = v.w;
    }
    const float* xr = x + n * PER_SAMPLE + sp + tok;
    float* yp = y + (size_t)(s0 + tok) * 64;
    for (int k = 0; k < 16; k++) {
        int c = cg * 16 + k;
        const float* wr = proj_w + c * 64;
        float s = proj_b[c];
#pragma unroll
        for (int cc = 0; cc < 64; cc++) s += av[cc] * wr[cc];
        s += xr[c * SPATIAL];       // + x1 residual (NCHW transposed read)
        yp[c] = s;
    }
}

// ---------------- K5a: LN + fc1 + exact GELU ----------------
__global__ __launch_bounds__(256) void k_fc1(const float* __restrict__ y,
                                             const float* __restrict__ ln_w,
                                             const float* __restrict__ ln_b,
                                             const float* __restrict__ fc1_w,
                                             const float* __restrict__ fc1_b,
                                             float* __restrict__ hdn) {
    int s0 = blockIdx.x * 64;
    int t = threadIdx.x, tok = t & 63, jg = t >> 6;

    float yv[64];
    const float4* yp = (const float4*)(y + (size_t)(s0 + tok) * 64);
#pragma unroll
    for (int i = 0; i < 16; i++) {
        float4 v = yp[i];
        yv[4 * i] = v.x; yv[4 * i + 1] = v.y; yv[4 * i + 2] = v.z; yv[4 * i + 3] = v.w;
    }
    float mu = 0.f;
#pragma unroll
    for (int c = 0; c < 64; c++) mu += yv[c];
    mu *= (1.f / 64.f);
    float var = 0.f;
#pragma unroll
    for (int c = 0; c < 64; c++) { float d = yv[c] - mu; var += d * d; }
    var *= (1.f / 64.f);
    float rstd = rsqrtf(var + EPS);
#pragma unroll
    for (int c = 0; c < 64; c++)
        yv[c] = (yv[c] - mu) * rstd * ln_w[c] + ln_b[c];

    float* hp = hdn + (size_t)(s0 + tok) * 256 + jg * 64;
    for (int k = 0; k < 64; k++) {
        int j = jg * 64 + k;
        const float* wr = fc1_w + j * 64;
        float s = fc1_b[j];
#pragma unroll
        for (int c = 0; c < 64; c++) s += yv[c] * wr[c];
        // exact gelu: 0.5*x*(1+erf(x/sqrt(2)))
        hp[k] = 0.5f * s * (1.f + erff(s * 0.70710678118654752f));
    }
}

// ---------------- K5b: fc2 + residual + NCHW transposed store ----------------
__global__ __launch_bounds__(256) void k_fc2(const float* __restrict__ hdn,
                                             const float* __restrict__ fc2_w,
                                             const float* __restrict__ fc2_b,
                                             const float* __restrict__ y,
                                             float* __restrict__ out) {
    int s0 = blockIdx.x * 64;
    int n = s0 >> 12, sp = s0 & 4095;
    int t = threadIdx.x, tok = t & 63, cg = t >> 6;

    float acc[16];
#pragma unroll
    for (int k = 0; k < 16; k++) acc[k] = 0.f;

    for (int jb = 0; jb < 4; jb++) {
        float hv[64];
        const float4* hp = (const float4*)(hdn + (size_t)(s0 + tok) * 256 + jb * 64);
#pragma unroll
        for (int i = 0; i < 16; i++) {
            float4 v = hp[i];
            hv[4 * i] = v.x; hv[4 * i + 1] = v.y; hv[4 * i + 2] = v.z; hv[4 * i + 3] = v.w;
        }
#pragma unroll
        for (int k = 0; k < 16; k++) {
            int c = cg * 16 + k;
            const float* wr = fc2_w + c * 256 + jb * 64;
#pragma unroll
            for (int jj = 0; jj < 64; jj++) acc[k] += hv[jj] * wr[jj];
        }
    }
    const float* yp = y + (size_t)(s0 + tok) * 64;
    float* op = out + (size_t)n * PER_SAMPLE + sp + tok;
#pragma unroll
    for (int k = 0; k < 16; k++) {
        int c = cg * 16 + k;
        op[c * SPATIAL] = acc[k] + fc2_b[c] + yp[c];
    }
}

extern "C" void kernel_launch(void* const* d_in, const int* in_sizes, int n_in,
                              void* d_out, int out_size, void* d_ws, size_t ws_size,
                              hipStream_t stream) {
    const float* x      = (const float*)d_in[0];
    const float* gn_w   = (const float*)d_in[1];
    const float* gn_b   = (const float*)d_in[2];
    const float* qkv_w  = (const float*)d_in[3];
    const float* qkv_b  = (const float*)d_in[4];
    const float* rpb    = (const float*)d_in[5];
    const float* proj_w = (const float*)d_in[6];
    const float* proj_b = (const float*)d_in[7];
    const float* ln_w   = (const float*)d_in[8];
    const float* ln_b   = (const float*)d_in[9];
    const float* fc1_w  = (const float*)d_in[10];
    const float* fc1_b  = (const float*)d_in[11];
    const float* fc2_w  = (const float*)d_in[12];
    const float* fc2_b  = (const float*)d_in[13];
    float* out = (float*)d_out;

    float* ws      = (float*)d_ws;
    float* stats   = ws;                        // 16 floats
    float* qkv     = ws + 64;                   // 32768*192 = 6291456
    float* attnout = qkv + (size_t)NTOK * 192;  // 32768*64  = 2097152
    float* y       = attnout + (size_t)NTOK * 64;
    float* hdn     = qkv;                       // alias dead qkv+attnout (33.5MB <= 33.6MB)

    hipMemsetAsync(stats, 0, 64, stream);
    k_stats<<<256, 256, 0, stream>>>(x, stats);
    k_qkv  <<<512, 256, 0, stream>>>(x, stats, gn_w, gn_b, qkv_w, qkv_b, qkv);
    k_attn <<<512, 256, 0, stream>>>(qkv, rpb, attnout);
    k_proj <<<512, 256, 0, stream>>>(attnout, proj_w, proj_b, x, y);
    k_fc1  <<<512, 256, 0, stream>>>(y, ln_w, ln_b, fc1_w, fc1_b, hdn);
    k_fc2  <<<512, 256, 0, stream>>>(hdn, fc2_w, fc2_b, y, out);
}